// Round 1
// baseline (309.456 us; speedup 1.0000x reference)
//
#include <hip/hip_runtime.h>
#include <stdint.h>

#define B_ 2
#define CTX_ 4096
#define DRAFT_ 512
#define D_ 2048
#define H_ 16
#define KVH_ 4
#define HD_ 128
#define TOT_ 4608

using bf16x8 = __attribute__((ext_vector_type(8))) short;
using f32x4  = __attribute__((ext_vector_type(4))) float;

__device__ __forceinline__ unsigned short f2bf(float x) {
  unsigned int u = __float_as_uint(x);
  u += 0x7fffu + ((u >> 16) & 1u);
  return (unsigned short)(u >> 16);
}

__device__ __forceinline__ void gload16(const void* g, void* l) {
  __builtin_amdgcn_global_load_lds((const __attribute__((address_space(1))) void*)g,
                                   (__attribute__((address_space(3))) void*)l, 16, 0, 0);
}

// ---------------------------------------------------------------------------
// Fused fp32 -> bf16 conversion: kv concat (context||draft per batch) + weights
// ---------------------------------------------------------------------------
__global__ __launch_bounds__(256, 4)
void conv_kernel(const float* __restrict__ ctx, const float* __restrict__ draft,
                 const float* __restrict__ wq, const float* __restrict__ wk,
                 const float* __restrict__ wv, const float* __restrict__ wo,
                 unsigned short* __restrict__ kv, unsigned short* __restrict__ wqb,
                 unsigned short* __restrict__ wkb, unsigned short* __restrict__ wvb,
                 unsigned short* __restrict__ wob) {
  long t = (long)blockIdx.x * 256 + threadIdx.x;
  const long NKV = (long)B_ * TOT_ * D_ / 8;  // 2359296
  const long NWQ = 2048L * 2048 / 8;          // 524288
  const long NWK = 512L * 2048 / 8;           // 131072
  const float* src;
  unsigned short* dst;
  if (t < NKV) {
    long i = t * 8;
    int b = (int)(i / ((long)TOT_ * D_));
    long rem = i - (long)b * TOT_ * D_;
    int r = (int)(rem / D_);
    int c = (int)(rem - (long)r * D_);
    if (r < CTX_) src = ctx + ((long)(b * CTX_ + r)) * D_ + c;
    else          src = draft + ((long)(b * DRAFT_ + (r - CTX_))) * D_ + c;
    dst = kv + i;
  } else if (t < NKV + NWQ) {
    long l = t - NKV; src = wq + l * 8; dst = wqb + l * 8;
  } else if (t < NKV + NWQ + NWK) {
    long l = t - NKV - NWQ; src = wk + l * 8; dst = wkb + l * 8;
  } else if (t < NKV + NWQ + 2 * NWK) {
    long l = t - NKV - NWQ - NWK; src = wv + l * 8; dst = wvb + l * 8;
  } else {
    long l = t - NKV - NWQ - 2 * NWK; src = wo + l * 8; dst = wob + l * 8;
  }
  float4 a = ((const float4*)src)[0];
  float4 b4 = ((const float4*)src)[1];
  uint4 o;
  o.x = (unsigned)f2bf(a.x) | ((unsigned)f2bf(a.y) << 16);
  o.y = (unsigned)f2bf(a.z) | ((unsigned)f2bf(a.w) << 16);
  o.z = (unsigned)f2bf(b4.x) | ((unsigned)f2bf(b4.y) << 16);
  o.w = (unsigned)f2bf(b4.z) | ((unsigned)f2bf(b4.w) << 16);
  *((uint4*)dst) = o;
}

// ---------------------------------------------------------------------------
// bf16 GEMM: C[M,N] = A[M,K] @ W[N,K]^T  (both row-major, K contiguous)
// BK=64, global_load_lds staging, XOR-swizzled LDS, 16x16x32 bf16 MFMA.
// 4 waves in 2x2, each wave computes (BM/2)x(BN/2).
// ---------------------------------------------------------------------------
template <int BM, int BN>
__global__ __launch_bounds__(256, 2)
void gemm_bt(const unsigned short* __restrict__ A, const unsigned short* __restrict__ W,
             float* __restrict__ C, int K, int N, long batchA, long batchC) {
  constexpr int MT = BM / 32;  // m-frags per wave
  constexpr int NT = BN / 32;  // n-frags per wave
  __shared__ unsigned short lds[(BM + BN) * 64];
  unsigned short* As = lds;
  unsigned short* Bs = lds + BM * 64;
  const int tid = threadIdx.x;
  const int lane = tid & 63, wid = tid >> 6;
  const int g = lane >> 4, r16 = lane & 15;
  const int wm = wid >> 1, wn = wid & 1;

  A += (long)blockIdx.z * batchA + (long)blockIdx.x * BM * K;
  W += (long)blockIdx.y * BN * K;
  C += (long)blockIdx.z * batchC + (long)blockIdx.x * BM * N + (long)blockIdx.y * BN;

  f32x4 zero = {0.f, 0.f, 0.f, 0.f};
  f32x4 acc[MT][NT];
#pragma unroll
  for (int i = 0; i < MT; ++i)
#pragma unroll
    for (int j = 0; j < NT; ++j) acc[i][j] = zero;

  for (int kb = 0; kb < K; kb += 64) {
#pragma unroll
    for (int is = 0; is < BM / 32; ++is) {
      int row = is * 32 + (tid >> 3);
      int sl = (tid & 7) ^ (row & 7);
      gload16(A + (long)row * K + kb + sl * 8, As + is * 2048 + wid * 512);
    }
#pragma unroll
    for (int is = 0; is < BN / 32; ++is) {
      int row = is * 32 + (tid >> 3);
      int sl = (tid & 7) ^ (row & 7);
      gload16(W + (long)row * K + kb + sl * 8, Bs + is * 2048 + wid * 512);
    }
    __syncthreads();
#pragma unroll
    for (int kh = 0; kh < 2; ++kh) {
      bf16x8 af[MT], bfr[NT];
#pragma unroll
      for (int i = 0; i < MT; ++i) {
        int row = wm * (BM / 2) + i * 16 + r16;
        int sl = (kh * 4 + g) ^ (row & 7);
        af[i] = *(const bf16x8*)(As + row * 64 + sl * 8);
      }
#pragma unroll
      for (int j = 0; j < NT; ++j) {
        int row = wn * (BN / 2) + j * 16 + r16;
        int sl = (kh * 4 + g) ^ (row & 7);
        bfr[j] = *(const bf16x8*)(Bs + row * 64 + sl * 8);
      }
#pragma unroll
      for (int i = 0; i < MT; ++i)
#pragma unroll
        for (int j = 0; j < NT; ++j)
          acc[i][j] = __builtin_amdgcn_mfma_f32_16x16x32_bf16(af[i], bfr[j], acc[i][j], 0, 0, 0);
    }
    __syncthreads();
  }
#pragma unroll
  for (int i = 0; i < MT; ++i)
#pragma unroll
    for (int j = 0; j < NT; ++j)
#pragma unroll
      for (int e = 0; e < 4; ++e) {
        int row = wm * (BM / 2) + i * 16 + g * 4 + e;
        int col = wn * (BN / 2) + j * 16 + r16;
        C[(long)row * N + col] = acc[i][j][e];
      }
}

// ---------------------------------------------------------------------------
// Fused post: Q RMSNorm+RoPE (+fold SCALE*log2e), K RMSNorm+RoPE, V transpose.
// One wave per (b,s,head) row; lane j handles d=j and d=j+64 (RoPE pair).
// ---------------------------------------------------------------------------
__global__ __launch_bounds__(256, 4)
void post_kernel(const float* __restrict__ qraw, const float* __restrict__ kraw,
                 const float* __restrict__ vraw, const float* __restrict__ qw,
                 const float* __restrict__ kw, const int* __restrict__ cpos,
                 const int* __restrict__ dpos, unsigned short* __restrict__ qatt,
                 unsigned short* __restrict__ katt, unsigned short* __restrict__ vt) {
  const int QB = (B_ * DRAFT_ * H_) / 4;  // 4096
  const int KB = (B_ * TOT_ * KVH_) / 4;  // 9216
  int bid = blockIdx.x;
  int tid = threadIdx.x;
  int lane = tid & 63, wid = tid >> 6;
  if (bid < QB + KB) {
    bool isQ = (bid < QB);
    int row = (isQ ? bid : bid - QB) * 4 + wid;
    const float* src;
    const float* wnorm;
    int pos;
    float fold;
    unsigned short* dst;
    if (isQ) {
      int b = row >> 13;           // /(512*16)
      int r2 = row & 8191;
      int s = r2 >> 4, hh = r2 & 15;
      src = qraw + (long)row * 128;  // [(b*512+s)*16+hh]*128
      wnorm = qw;
      pos = dpos[b * DRAFT_ + s];
      fold = 0.08838834764831843f * 1.4426950408889634f;  // SCALE * log2(e)
      dst = qatt + ((long)(b * H_ + hh) * DRAFT_ + s) * 128;
    } else {
      int b = row / (TOT_ * KVH_);
      int r2 = row - b * (TOT_ * KVH_);
      int s = r2 >> 2, hh = r2 & 3;
      src = kraw + (long)row * 128;  // [(b*4608+s)*4+hh]*128
      wnorm = kw;
      pos = (s < CTX_) ? cpos[b * CTX_ + s] : dpos[b * DRAFT_ + (s - CTX_)];
      fold = 1.0f;
      dst = katt + ((long)(b * KVH_ + hh) * TOT_ + s) * 128;
    }
    float x1 = src[lane], x2 = src[lane + 64];
    float ss = x1 * x1 + x2 * x2;
#pragma unroll
    for (int off = 1; off < 64; off <<= 1) ss += __shfl_xor(ss, off);
    float rn = rsqrtf(ss * 0.0078125f + 1e-6f);
    float y1 = wnorm[lane] * x1 * rn;
    float y2 = wnorm[lane + 64] * x2 * rn;
    float invf = exp2f((float)lane * -0.20762050593046014f);  // 10000^(-lane/64)
    float fr = (float)pos * invf;
    float sn, cs;
    sincosf(fr, &sn, &cs);
    dst[lane] = f2bf((y1 * cs - y2 * sn) * fold);
    dst[lane + 64] = f2bf((y2 * cs + y1 * sn) * fold);
  } else {
    // V transpose: vraw [B][TOT][KVH*128] fp32 -> vt [B*KVH][128][TOT] bf16
    long t = (long)(bid - (QB + KB)) * 256 + tid;
    int d = (int)(t & 127);
    int rest = (int)(t >> 7);  // [0, 4608)
    int sc = rest % 576, bk = rest / 576;
    int b = bk >> 2, kvh = bk & 3;
    int s0 = sc * 8;
    const float* src = vraw + ((long)(b * TOT_ + s0)) * 512 + kvh * 128 + d;
    unsigned int o[4];
#pragma unroll
    for (int jj = 0; jj < 4; ++jj) {
      unsigned short lo = f2bf(src[(2 * jj) * 512]);
      unsigned short hi = f2bf(src[(2 * jj + 1) * 512]);
      o[jj] = (unsigned)lo | ((unsigned)hi << 16);
    }
    uint4 ov = make_uint4(o[0], o[1], o[2], o[3]);
    *((uint4*)(vt + ((long)(bk * 128 + d)) * TOT_ + s0)) = ov;
  }
}

// ---------------------------------------------------------------------------
// Flash attention: block = (b, h, 64 q-rows), 4 waves x 16 q-rows.
// Swapped QK^T (S^T = K*Q), online softmax (log2 domain), O^T = V^T * P^T.
// K tile [64 keys][128] and Vt tile [128 d][64 keys] staged in swizzled LDS.
// ---------------------------------------------------------------------------
__global__ __launch_bounds__(256, 2)
void attn_kernel(const unsigned short* __restrict__ Q, const unsigned short* __restrict__ Kt,
                 const unsigned short* __restrict__ Vt, unsigned short* __restrict__ Oa) {
  __shared__ unsigned short lds[64 * 128 + 128 * 64];
  unsigned short* Ks = lds;
  unsigned short* Vs = lds + 64 * 128;
  const int tid = threadIdx.x, lane = tid & 63, wid = tid >> 6;
  const int g = lane >> 4, r16 = lane & 15;
  const int q0 = blockIdx.x, h = blockIdx.y, b = blockIdx.z;
  const int kvh = h >> 2;

  const unsigned short* Qrow =
      Q + ((long)(b * H_ + h) * DRAFT_ + q0 * 64 + wid * 16 + r16) * 128;
  bf16x8 qf[4];
#pragma unroll
  for (int kb = 0; kb < 4; ++kb) qf[kb] = *(const bf16x8*)(Qrow + kb * 32 + g * 8);

  f32x4 zero = {0.f, 0.f, 0.f, 0.f};
  f32x4 acc[8];
#pragma unroll
  for (int nb = 0; nb < 8; ++nb) acc[nb] = zero;
  float m_run = -1e30f, l_run = 0.0f;

  const unsigned short* Kbase = Kt + (long)(b * KVH_ + kvh) * TOT_ * 128;
  const unsigned short* Vbase = Vt + (long)(b * KVH_ + kvh) * 128L * TOT_;

  for (int s0 = 0; s0 < TOT_; s0 += 64) {
#pragma unroll
    for (int is = 0; is < 4; ++is) {
      int row = is * 16 + (tid >> 4);
      int sl = (tid & 15) ^ (row & 7);
      gload16(Kbase + (long)(s0 + row) * 128 + sl * 8, Ks + is * 2048 + wid * 512);
    }
#pragma unroll
    for (int is = 0; is < 4; ++is) {
      int d = is * 32 + (tid >> 3);
      int sl = (tid & 7) ^ (d & 7);
      gload16(Vbase + (long)d * TOT_ + s0 + sl * 8, Vs + is * 2048 + wid * 512);
    }
    __syncthreads();

    // S^T = K_tile * Q : D[key][q]
    f32x4 st[4];
#pragma unroll
    for (int h2 = 0; h2 < 4; ++h2) st[h2] = zero;
#pragma unroll
    for (int h2 = 0; h2 < 4; ++h2) {
      int row = h2 * 16 + r16;
#pragma unroll
      for (int kb = 0; kb < 4; ++kb) {
        int sl = (kb * 4 + g) ^ (row & 7);
        bf16x8 a = *(const bf16x8*)(Ks + row * 128 + sl * 8);
        st[h2] = __builtin_amdgcn_mfma_f32_16x16x32_bf16(a, qf[kb], st[h2], 0, 0, 0);
      }
    }
    // online softmax over keys (rows of S^T), per q = r16
    float tmax = -1e30f;
#pragma unroll
    for (int h2 = 0; h2 < 4; ++h2)
#pragma unroll
      for (int e = 0; e < 4; ++e) tmax = fmaxf(tmax, st[h2][e]);
    tmax = fmaxf(tmax, __shfl_xor(tmax, 16));
    tmax = fmaxf(tmax, __shfl_xor(tmax, 32));
    float m_new = fmaxf(m_run, tmax);
    float scale = exp2f(m_run - m_new);
    float tsum = 0.0f;
#pragma unroll
    for (int h2 = 0; h2 < 4; ++h2)
#pragma unroll
      for (int e = 0; e < 4; ++e) {
        float p = exp2f(st[h2][e] - m_new);
        st[h2][e] = p;
        tsum += p;
      }
    tsum += __shfl_xor(tsum, 16);
    tsum += __shfl_xor(tsum, 32);
    l_run = l_run * scale + tsum;
    m_run = m_new;
#pragma unroll
    for (int nb = 0; nb < 8; ++nb) acc[nb] = acc[nb] * scale;

    // pack P^T to bf16
    unsigned int pk0[4], pk1[4];
#pragma unroll
    for (int h2 = 0; h2 < 4; ++h2) {
      pk0[h2] = (unsigned)f2bf(st[h2][0]) | ((unsigned)f2bf(st[h2][1]) << 16);
      pk1[h2] = (unsigned)f2bf(st[h2][2]) | ((unsigned)f2bf(st[h2][3]) << 16);
    }
    // PV: O^T += V^T * P^T
#pragma unroll
    for (int kb2 = 0; kb2 < 2; ++kb2) {
      int src0 = ((g & 1) * 2) * 16 + r16;
      int src1 = src0 + 16;
      int lo0a = __shfl((int)pk0[kb2 * 2], src0);
      int lo0b = __shfl((int)pk0[kb2 * 2 + 1], src0);
      int lo1a = __shfl((int)pk1[kb2 * 2], src0);
      int lo1b = __shfl((int)pk1[kb2 * 2 + 1], src0);
      int hi0a = __shfl((int)pk0[kb2 * 2], src1);
      int hi0b = __shfl((int)pk0[kb2 * 2 + 1], src1);
      int hi1a = __shfl((int)pk1[kb2 * 2], src1);
      int hi1b = __shfl((int)pk1[kb2 * 2 + 1], src1);
      bool top = (g >= 2);
      union {
        int i[4];
        bf16x8 v;
      } pb;
      pb.i[0] = top ? lo0b : lo0a;
      pb.i[1] = top ? lo1b : lo1a;
      pb.i[2] = top ? hi0b : hi0a;
      pb.i[3] = top ? hi1b : hi1a;
#pragma unroll
      for (int nb = 0; nb < 8; ++nb) {
        int d = nb * 16 + r16;
        int sl = (kb2 * 4 + g) ^ (d & 7);
        bf16x8 a = *(const bf16x8*)(Vs + d * 64 + sl * 8);
        acc[nb] = __builtin_amdgcn_mfma_f32_16x16x32_bf16(a, pb.v, acc[nb], 0, 0, 0);
      }
    }
    __syncthreads();
  }
  float inv = 1.0f / l_run;
  long obase = (((long)(b * DRAFT_ + q0 * 64 + wid * 16 + r16)) * H_ + h) * 128;
#pragma unroll
  for (int nb = 0; nb < 8; ++nb)
#pragma unroll
    for (int e = 0; e < 4; ++e)
      Oa[obase + nb * 16 + g * 4 + e] = f2bf(acc[nb][e] * inv);
}

// ---------------------------------------------------------------------------
extern "C" void kernel_launch(void* const* d_in, const int* in_sizes, int n_in,
                              void* d_out, int out_size, void* d_ws, size_t ws_size,
                              hipStream_t stream) {
  const float* draft = (const float*)d_in[0];
  const float* ctx = (const float*)d_in[1];
  const float* Wq = (const float*)d_in[2];
  const float* Wk = (const float*)d_in[3];
  const float* Wv = (const float*)d_in[4];
  const float* Wo = (const float*)d_in[5];
  const float* qw = (const float*)d_in[6];
  const float* kw = (const float*)d_in[7];
  const int* cpos = (const int*)d_in[8];
  const int* dpos = (const int*)d_in[9];

  char* ws = (char*)d_ws;
  unsigned short* kvb = (unsigned short*)(ws + 0);          // 37,748,736 B
  unsigned short* wqb = (unsigned short*)(ws + 37748736);   //  8,388,608
  unsigned short* wkb = (unsigned short*)(ws + 46137344);   //  2,097,152
  unsigned short* wvb = (unsigned short*)(ws + 48234496);   //  2,097,152
  unsigned short* wob = (unsigned short*)(ws + 50331648);   //  8,388,608
  float* qraw = (float*)(ws + 58720256);                    //  8,388,608
  float* kraw = (float*)(ws + 67108864);                    // 18,874,368
  float* vraw = (float*)(ws + 85983232);                    // 18,874,368
  unsigned short* qatt = (unsigned short*)(ws + 104857600); //  4,194,304
  unsigned short* katt = (unsigned short*)(ws + 109051904); //  9,437,184
  unsigned short* vtb = (unsigned short*)(ws + 118489088);  //  9,437,184
  unsigned short* attb = (unsigned short*)(ws + 127926272); //  4,194,304
  // total 132,120,576 B

  // 1. convert inputs/weights to bf16 (kv = context||draft per batch)
  conv_kernel<<<dim3(14336), 256, 0, stream>>>(ctx, draft, Wq, Wk, Wv, Wo, kvb, wqb,
                                               wkb, wvb, wob);
  // 2. Q = draft @ Wq^T  (per-batch base into kv's draft rows)
  gemm_bt<64, 128><<<dim3(8, 16, 2), 256, 0, stream>>>(
      kvb + (long)CTX_ * D_, wqb, qraw, 2048, 2048, (long)TOT_ * D_, (long)DRAFT_ * D_);
  // 3. K = kv @ Wk^T
  gemm_bt<128, 128><<<dim3(72, 4, 1), 256, 0, stream>>>(kvb, wkb, kraw, 2048, 512, 0, 0);
  // 4. V = kv @ Wv^T
  gemm_bt<128, 128><<<dim3(72, 4, 1), 256, 0, stream>>>(kvb, wvb, vraw, 2048, 512, 0, 0);
  // 5. RMSNorm+RoPE for Q,K; transpose V
  post_kernel<<<dim3(15616), 256, 0, stream>>>(qraw, kraw, vraw, qw, kw, cpos, dpos,
                                               qatt, katt, vtb);
  // 6. attention
  attn_kernel<<<dim3(8, 16, 2), 256, 0, stream>>>(qatt, katt, vtb, attb);
  // 7. out = attn @ Wo^T
  gemm_bt<64, 128><<<dim3(16, 16, 1), 256, 0, stream>>>(attb, wob, (float*)d_out, 2048,
                                                        2048, 0, 0);
}

// Round 2
// 204.510 us; speedup vs baseline: 1.5132x; 1.5132x over previous
//
#include <hip/hip_runtime.h>
#include <stdint.h>

#define B_ 2
#define CTX_ 4096
#define DRAFT_ 512
#define D_ 2048
#define H_ 16
#define KVH_ 4
#define HD_ 128
#define TOT_ 4608
#define NSPLIT 4
#define SPLIT_LEN (TOT_ / NSPLIT)  // 1152

using bf16x8 = __attribute__((ext_vector_type(8))) short;
using f32x4  = __attribute__((ext_vector_type(4))) float;

__device__ __forceinline__ unsigned short f2bf(float x) {
  unsigned int u = __float_as_uint(x);
  u += 0x7fffu + ((u >> 16) & 1u);
  return (unsigned short)(u >> 16);
}

__device__ __forceinline__ unsigned cvtpk(float lo, float hi) {
  unsigned r;
  asm("v_cvt_pk_bf16_f32 %0, %1, %2" : "=v"(r) : "v"(lo), "v"(hi));
  return r;
}

__device__ __forceinline__ void gload16(const void* g, void* l) {
  __builtin_amdgcn_global_load_lds((const __attribute__((address_space(1))) void*)g,
                                   (__attribute__((address_space(3))) void*)l, 16, 0, 0);
}

// ---------------------------------------------------------------------------
// Fused fp32 -> bf16 conversion: kv concat (context||draft per batch) + weights
// (wk and wv write adjacent buffers -> concatenated [1024,2048] KV weight)
// ---------------------------------------------------------------------------
__global__ __launch_bounds__(256, 4)
void conv_kernel(const float* __restrict__ ctx, const float* __restrict__ draft,
                 const float* __restrict__ wq, const float* __restrict__ wk,
                 const float* __restrict__ wv, const float* __restrict__ wo,
                 unsigned short* __restrict__ kv, unsigned short* __restrict__ wqb,
                 unsigned short* __restrict__ wkb, unsigned short* __restrict__ wvb,
                 unsigned short* __restrict__ wob) {
  long t = (long)blockIdx.x * 256 + threadIdx.x;
  const long NKV = (long)B_ * TOT_ * D_ / 8;  // 2359296
  const long NWQ = 2048L * 2048 / 8;          // 524288
  const long NWK = 512L * 2048 / 8;           // 131072
  const float* src;
  unsigned short* dst;
  if (t < NKV) {
    long i = t * 8;
    int b = (int)(i / ((long)TOT_ * D_));
    long rem = i - (long)b * TOT_ * D_;
    int r = (int)(rem / D_);
    int c = (int)(rem - (long)r * D_);
    if (r < CTX_) src = ctx + ((long)(b * CTX_ + r)) * D_ + c;
    else          src = draft + ((long)(b * DRAFT_ + (r - CTX_))) * D_ + c;
    dst = kv + i;
  } else if (t < NKV + NWQ) {
    long l = t - NKV; src = wq + l * 8; dst = wqb + l * 8;
  } else if (t < NKV + NWQ + NWK) {
    long l = t - NKV - NWQ; src = wk + l * 8; dst = wkb + l * 8;
  } else if (t < NKV + NWQ + 2 * NWK) {
    long l = t - NKV - NWQ - NWK; src = wv + l * 8; dst = wvb + l * 8;
  } else {
    long l = t - NKV - NWQ - 2 * NWK; src = wo + l * 8; dst = wob + l * 8;
  }
  float4 a = ((const float4*)src)[0];
  float4 b4 = ((const float4*)src)[1];
  uint4 o;
  o.x = (unsigned)f2bf(a.x) | ((unsigned)f2bf(a.y) << 16);
  o.y = (unsigned)f2bf(a.z) | ((unsigned)f2bf(a.w) << 16);
  o.z = (unsigned)f2bf(b4.x) | ((unsigned)f2bf(b4.y) << 16);
  o.w = (unsigned)f2bf(b4.z) | ((unsigned)f2bf(b4.w) << 16);
  *((uint4*)dst) = o;
}

// ---------------------------------------------------------------------------
// bf16 GEMM body: C[BM,BN] tile of A[.,kLen] @ W[.,kLen]^T, row stride ld.
// BK=64, global_load_lds staging, XOR-swizzled LDS, 16x16x32 bf16 MFMA.
// 4 waves in 2x2, each wave computes (BM/2)x(BN/2).
// ---------------------------------------------------------------------------
template <int BM, int BN>
__device__ __forceinline__ void gemm_body(const unsigned short* __restrict__ A,
                                          const unsigned short* __restrict__ W,
                                          float* __restrict__ C, int ld, int kLen,
                                          int N, unsigned short* lds) {
  constexpr int MT = BM / 32;
  constexpr int NT = BN / 32;
  unsigned short* As = lds;
  unsigned short* Bs = lds + BM * 64;
  const int tid = threadIdx.x;
  const int lane = tid & 63, wid = tid >> 6;
  const int g = lane >> 4, r16 = lane & 15;
  const int wm = wid >> 1, wn = wid & 1;

  f32x4 zero = {0.f, 0.f, 0.f, 0.f};
  f32x4 acc[MT][NT];
#pragma unroll
  for (int i = 0; i < MT; ++i)
#pragma unroll
    for (int j = 0; j < NT; ++j) acc[i][j] = zero;

  for (int kb = 0; kb < kLen; kb += 64) {
#pragma unroll
    for (int is = 0; is < BM / 32; ++is) {
      int row = is * 32 + (tid >> 3);
      int sl = (tid & 7) ^ (row & 7);
      gload16(A + (long)row * ld + kb + sl * 8, As + is * 2048 + wid * 512);
    }
#pragma unroll
    for (int is = 0; is < BN / 32; ++is) {
      int row = is * 32 + (tid >> 3);
      int sl = (tid & 7) ^ (row & 7);
      gload16(W + (long)row * ld + kb + sl * 8, Bs + is * 2048 + wid * 512);
    }
    __syncthreads();
#pragma unroll
    for (int kh = 0; kh < 2; ++kh) {
      bf16x8 af[MT], bfr[NT];
#pragma unroll
      for (int i = 0; i < MT; ++i) {
        int row = wm * (BM / 2) + i * 16 + r16;
        int sl = (kh * 4 + g) ^ (row & 7);
        af[i] = *(const bf16x8*)(As + row * 64 + sl * 8);
      }
#pragma unroll
      for (int j = 0; j < NT; ++j) {
        int row = wn * (BN / 2) + j * 16 + r16;
        int sl = (kh * 4 + g) ^ (row & 7);
        bfr[j] = *(const bf16x8*)(Bs + row * 64 + sl * 8);
      }
#pragma unroll
      for (int i = 0; i < MT; ++i)
#pragma unroll
        for (int j = 0; j < NT; ++j)
          acc[i][j] = __builtin_amdgcn_mfma_f32_16x16x32_bf16(af[i], bfr[j], acc[i][j], 0, 0, 0);
    }
    __syncthreads();
  }
#pragma unroll
  for (int i = 0; i < MT; ++i)
#pragma unroll
    for (int j = 0; j < NT; ++j)
#pragma unroll
      for (int e = 0; e < 4; ++e) {
        int row = wm * (BM / 2) + i * 16 + g * 4 + e;
        int col = wn * (BN / 2) + j * 16 + r16;
        C[(long)row * N + col] = acc[i][j][e];
      }
}

// ---------------------------------------------------------------------------
// Combined QKV projection: blocks 0..127 -> Q (draft rows), 128..703 -> KV.
// ---------------------------------------------------------------------------
__global__ __launch_bounds__(256, 2)
void qkv_kernel(const unsigned short* __restrict__ kvb,
                const unsigned short* __restrict__ wqb,
                const unsigned short* __restrict__ wkvb, float* __restrict__ qraw,
                float* __restrict__ kvraw) {
  __shared__ unsigned short lds[256 * 64];
  int id = blockIdx.x;
  if (id < 128) {
    int b = id >> 6, mb = (id >> 4) & 3, nb = id & 15;
    const unsigned short* A = kvb + ((long)b * TOT_ + CTX_ + mb * 128) * 2048;
    const unsigned short* W = wqb + (long)nb * 128 * 2048;
    float* C = qraw + ((long)b * 512 + mb * 128) * 2048 + nb * 128;
    gemm_body<128, 128>(A, W, C, 2048, 2048, 2048, lds);
  } else {
    int id2 = id - 128;
    int mb = id2 >> 3, nb = id2 & 7;
    const unsigned short* A = kvb + (long)mb * 128 * 2048;
    const unsigned short* W = wkvb + (long)nb * 128 * 2048;
    float* C = kvraw + (long)mb * 128 * 1024 + nb * 128;
    gemm_body<128, 128>(A, W, C, 2048, 2048, 1024, lds);
  }
}

// ---------------------------------------------------------------------------
// O projection with split-K (grid.z = 2 halves of K) into fp32 partials.
// ---------------------------------------------------------------------------
__global__ __launch_bounds__(256, 2)
void ogemm_kernel(const unsigned short* __restrict__ attb,
                  const unsigned short* __restrict__ wob, float* __restrict__ oP) {
  __shared__ unsigned short lds[192 * 64];
  int mb = blockIdx.x, nb = blockIdx.y, z = blockIdx.z;
  const unsigned short* A = attb + (long)mb * 64 * 2048 + z * 1024;
  const unsigned short* W = wob + (long)nb * 128 * 2048 + z * 1024;
  float* C = oP + (long)z * 1024 * 2048 + (long)mb * 64 * 2048 + nb * 128;
  gemm_body<64, 128>(A, W, C, 2048, 1024, 2048, lds);
}

__global__ __launch_bounds__(256, 4)
void addo_kernel(const float* __restrict__ oP, float* __restrict__ out) {
  long t = (long)blockIdx.x * 256 + threadIdx.x;
  float4 a = ((const float4*)oP)[t];
  float4 b = ((const float4*)(oP + 1024L * 2048))[t];
  ((float4*)out)[t] = make_float4(a.x + b.x, a.y + b.y, a.z + b.z, a.w + b.w);
}

// ---------------------------------------------------------------------------
// Fused post: Q RMSNorm+RoPE (+fold SCALE*log2e), K RMSNorm+RoPE, V transpose.
// kvraw layout: [B*TOT][1024] with K in cols 0..511, V in cols 512..1023.
// ---------------------------------------------------------------------------
__global__ __launch_bounds__(256, 4)
void post_kernel(const float* __restrict__ qraw, const float* __restrict__ kvraw,
                 const float* __restrict__ qw, const float* __restrict__ kw,
                 const int* __restrict__ cpos, const int* __restrict__ dpos,
                 unsigned short* __restrict__ qatt, unsigned short* __restrict__ katt,
                 unsigned short* __restrict__ vt) {
  const int QB = (B_ * DRAFT_ * H_) / 4;  // 4096
  const int KB = (B_ * TOT_ * KVH_) / 4;  // 9216
  int bid = blockIdx.x;
  int tid = threadIdx.x;
  int lane = tid & 63, wid = tid >> 6;
  if (bid < QB + KB) {
    bool isQ = (bid < QB);
    int row = (isQ ? bid : bid - QB) * 4 + wid;
    const float* src;
    const float* wnorm;
    int pos;
    float fold;
    unsigned short* dst;
    if (isQ) {
      int b = row >> 13;
      int r2 = row & 8191;
      int s = r2 >> 4, hh = r2 & 15;
      src = qraw + (long)row * 128;
      wnorm = qw;
      pos = dpos[b * DRAFT_ + s];
      fold = 0.08838834764831843f * 1.4426950408889634f;  // SCALE * log2(e)
      dst = qatt + ((long)(b * H_ + hh) * DRAFT_ + s) * 128;
    } else {
      int b = row / (TOT_ * KVH_);
      int r2 = row - b * (TOT_ * KVH_);
      int s = r2 >> 2, hh = r2 & 3;
      src = kvraw + ((long)(b * TOT_ + s)) * 1024 + hh * 128;
      wnorm = kw;
      pos = (s < CTX_) ? cpos[b * CTX_ + s] : dpos[b * DRAFT_ + (s - CTX_)];
      fold = 1.0f;
      dst = katt + ((long)(b * KVH_ + hh) * TOT_ + s) * 128;
    }
    float x1 = src[lane], x2 = src[lane + 64];
    float ss = x1 * x1 + x2 * x2;
#pragma unroll
    for (int off = 1; off < 64; off <<= 1) ss += __shfl_xor(ss, off);
    float rn = rsqrtf(ss * 0.0078125f + 1e-6f);
    float y1 = wnorm[lane] * x1 * rn;
    float y2 = wnorm[lane + 64] * x2 * rn;
    float invf = exp2f((float)lane * -0.20762050593046014f);  // 10000^(-lane/64)
    float fr = (float)pos * invf;
    float sn, cs;
    sincosf(fr, &sn, &cs);
    dst[lane] = f2bf((y1 * cs - y2 * sn) * fold);
    dst[lane + 64] = f2bf((y2 * cs + y1 * sn) * fold);
  } else {
    // V transpose: kvraw cols 512..1023 -> vt [B*KVH][128][TOT] bf16
    long t = (long)(bid - (QB + KB)) * 256 + tid;
    int d = (int)(t & 127);
    int rest = (int)(t >> 7);
    int sc = rest % 576, bk = rest / 576;
    int b = bk >> 2, kvh = bk & 3;
    int s0 = sc * 8;
    const float* src = kvraw + ((long)(b * TOT_ + s0)) * 1024 + 512 + kvh * 128 + d;
    unsigned int o[4];
#pragma unroll
    for (int jj = 0; jj < 4; ++jj) {
      unsigned short lo = f2bf(src[(2 * jj) * 1024]);
      unsigned short hi = f2bf(src[(2 * jj + 1) * 1024]);
      o[jj] = (unsigned)lo | ((unsigned)hi << 16);
    }
    uint4 ov = make_uint4(o[0], o[1], o[2], o[3]);
    *((uint4*)(vt + ((long)(bk * 128 + d)) * TOT_ + s0)) = ov;
  }
}

// ---------------------------------------------------------------------------
// Flash attention, split-K over the key axis (NSPLIT chunks).
// block = (q-block, h, b*NSPLIT+split); 4 waves x 16 q-rows.
// Swapped QK^T (S^T = K*Q), online softmax (log2 domain), O^T = V^T * P^T.
// Writes unnormalized partial O (fp32) + per-row (m,l).
// ---------------------------------------------------------------------------
__global__ __launch_bounds__(256, 4)
void attn_kernel(const unsigned short* __restrict__ Q, const unsigned short* __restrict__ Kt,
                 const unsigned short* __restrict__ Vt, float* __restrict__ pO,
                 float* __restrict__ pML) {
  __shared__ unsigned short lds[64 * 128 + 128 * 64];
  unsigned short* Ks = lds;
  unsigned short* Vs = lds + 64 * 128;
  const int tid = threadIdx.x, lane = tid & 63, wid = tid >> 6;
  const int g = lane >> 4, r16 = lane & 15;
  const int q0 = blockIdx.x, h = blockIdx.y;
  const int b = blockIdx.z >> 2, split = blockIdx.z & 3;
  const int kvh = h >> 2;

  const unsigned short* Qrow =
      Q + ((long)(b * H_ + h) * DRAFT_ + q0 * 64 + wid * 16 + r16) * 128;
  bf16x8 qf[4];
#pragma unroll
  for (int kb = 0; kb < 4; ++kb) qf[kb] = *(const bf16x8*)(Qrow + kb * 32 + g * 8);

  f32x4 zero = {0.f, 0.f, 0.f, 0.f};
  f32x4 acc[8];
#pragma unroll
  for (int nb = 0; nb < 8; ++nb) acc[nb] = zero;
  float m_run = -1e30f, l_run = 0.0f;

  const unsigned short* Kbase = Kt + (long)(b * KVH_ + kvh) * TOT_ * 128;
  const unsigned short* Vbase = Vt + (long)(b * KVH_ + kvh) * 128L * TOT_;

  const int sBeg = split * SPLIT_LEN, sEnd = sBeg + SPLIT_LEN;
  for (int s0 = sBeg; s0 < sEnd; s0 += 64) {
#pragma unroll
    for (int is = 0; is < 4; ++is) {
      int row = is * 16 + (tid >> 4);
      int sl = (tid & 15) ^ (row & 7);
      gload16(Kbase + (long)(s0 + row) * 128 + sl * 8, Ks + is * 2048 + wid * 512);
    }
#pragma unroll
    for (int is = 0; is < 4; ++is) {
      int d = is * 32 + (tid >> 3);
      int sl = (tid & 7) ^ (d & 7);
      gload16(Vbase + (long)d * TOT_ + s0 + sl * 8, Vs + is * 2048 + wid * 512);
    }
    __syncthreads();

    // S^T = K_tile * Q : D[key][q]
    f32x4 st[4];
#pragma unroll
    for (int h2 = 0; h2 < 4; ++h2) st[h2] = zero;
#pragma unroll
    for (int h2 = 0; h2 < 4; ++h2) {
      int row = h2 * 16 + r16;
#pragma unroll
      for (int kb = 0; kb < 4; ++kb) {
        int sl = (kb * 4 + g) ^ (row & 7);
        bf16x8 a = *(const bf16x8*)(Ks + row * 128 + sl * 8);
        st[h2] = __builtin_amdgcn_mfma_f32_16x16x32_bf16(a, qf[kb], st[h2], 0, 0, 0);
      }
    }
    // online softmax over keys (rows of S^T), per q = r16
    float tmax = -1e30f;
#pragma unroll
    for (int h2 = 0; h2 < 4; ++h2)
#pragma unroll
      for (int e = 0; e < 4; ++e) tmax = fmaxf(tmax, st[h2][e]);
    tmax = fmaxf(tmax, __shfl_xor(tmax, 16));
    tmax = fmaxf(tmax, __shfl_xor(tmax, 32));
    float m_new = fmaxf(m_run, tmax);
    float scale = exp2f(m_run - m_new);
    float tsum = 0.0f;
#pragma unroll
    for (int h2 = 0; h2 < 4; ++h2)
#pragma unroll
      for (int e = 0; e < 4; ++e) {
        float p = exp2f(st[h2][e] - m_new);
        st[h2][e] = p;
        tsum += p;
      }
    tsum += __shfl_xor(tsum, 16);
    tsum += __shfl_xor(tsum, 32);
    l_run = l_run * scale + tsum;
    m_run = m_new;
#pragma unroll
    for (int nb = 0; nb < 8; ++nb) acc[nb] = acc[nb] * scale;

    // pack P^T to bf16 (v_cvt_pk_bf16_f32)
    unsigned int pk0[4], pk1[4];
#pragma unroll
    for (int h2 = 0; h2 < 4; ++h2) {
      pk0[h2] = cvtpk(st[h2][0], st[h2][1]);
      pk1[h2] = cvtpk(st[h2][2], st[h2][3]);
    }
    // PV: O^T += V^T * P^T
#pragma unroll
    for (int kb2 = 0; kb2 < 2; ++kb2) {
      int src0 = ((g & 1) * 2) * 16 + r16;
      int src1 = src0 + 16;
      int lo0a = __shfl((int)pk0[kb2 * 2], src0);
      int lo0b = __shfl((int)pk0[kb2 * 2 + 1], src0);
      int lo1a = __shfl((int)pk1[kb2 * 2], src0);
      int lo1b = __shfl((int)pk1[kb2 * 2 + 1], src0);
      int hi0a = __shfl((int)pk0[kb2 * 2], src1);
      int hi0b = __shfl((int)pk0[kb2 * 2 + 1], src1);
      int hi1a = __shfl((int)pk1[kb2 * 2], src1);
      int hi1b = __shfl((int)pk1[kb2 * 2 + 1], src1);
      bool top = (g >= 2);
      union {
        int i[4];
        bf16x8 v;
      } pb;
      pb.i[0] = top ? lo0b : lo0a;
      pb.i[1] = top ? lo1b : lo1a;
      pb.i[2] = top ? hi0b : hi0a;
      pb.i[3] = top ? hi1b : hi1a;
#pragma unroll
      for (int nb = 0; nb < 8; ++nb) {
        int d = nb * 16 + r16;
        int sl = (kb2 * 4 + g) ^ (d & 7);
        bf16x8 a = *(const bf16x8*)(Vs + d * 64 + sl * 8);
        acc[nb] = __builtin_amdgcn_mfma_f32_16x16x32_bf16(a, pb.v, acc[nb], 0, 0, 0);
      }
    }
    __syncthreads();
  }
  const int q = q0 * 64 + wid * 16 + r16;
  const long rowIdx = ((long)(b * H_ + h)) * DRAFT_ + q;
  const long R = (long)B_ * H_ * DRAFT_;
  long pbase = ((long)split * R + rowIdx) * 128;
#pragma unroll
  for (int nb = 0; nb < 8; ++nb)
#pragma unroll
    for (int e = 0; e < 4; ++e) pO[pbase + nb * 16 + g * 4 + e] = acc[nb][e];
  if (g == 0) {
    pML[((long)split * R + rowIdx) * 2] = m_run;
    pML[((long)split * R + rowIdx) * 2 + 1] = l_run;
  }
}

// ---------------------------------------------------------------------------
// Combine split-K partials -> attb bf16 in [B*DRAFT][H*128] layout.
// ---------------------------------------------------------------------------
__global__ __launch_bounds__(256, 4)
void acomb_kernel(const float* __restrict__ pO, const float* __restrict__ pML,
                  unsigned short* __restrict__ attb) {
  const long R = (long)B_ * H_ * DRAFT_;  // 16384
  int row = blockIdx.x * 2 + (threadIdx.x >> 7);
  int d = threadIdx.x & 127;
  float m[NSPLIT], l[NSPLIT];
  float mmax = -1e30f;
#pragma unroll
  for (int i = 0; i < NSPLIT; ++i) {
    m[i] = pML[((long)i * R + row) * 2];
    l[i] = pML[((long)i * R + row) * 2 + 1];
    mmax = fmaxf(mmax, m[i]);
  }
  float ltot = 0.0f, o = 0.0f;
#pragma unroll
  for (int i = 0; i < NSPLIT; ++i) {
    float w = exp2f(m[i] - mmax);
    ltot += w * l[i];
    o += w * pO[((long)i * R + row) * 128 + d];
  }
  o /= ltot;
  int bh = row >> 9, q = row & 511;
  int b = bh >> 4, h = bh & 15;
  attb[(((long)(b * 512 + q) * 16 + h)) * 128 + d] = f2bf(o);
}

// ---------------------------------------------------------------------------
extern "C" void kernel_launch(void* const* d_in, const int* in_sizes, int n_in,
                              void* d_out, int out_size, void* d_ws, size_t ws_size,
                              hipStream_t stream) {
  const float* draft = (const float*)d_in[0];
  const float* ctx = (const float*)d_in[1];
  const float* Wq = (const float*)d_in[2];
  const float* Wk = (const float*)d_in[3];
  const float* Wv = (const float*)d_in[4];
  const float* Wo = (const float*)d_in[5];
  const float* qw = (const float*)d_in[6];
  const float* kw = (const float*)d_in[7];
  const int* cpos = (const int*)d_in[8];
  const int* dpos = (const int*)d_in[9];

  char* ws = (char*)d_ws;
  unsigned short* kvb = (unsigned short*)(ws + 0);          // 37,748,736 (dead after qkv)
  float* oP = (float*)(ws + 0);                             // 16,777,216 (aliases kvb)
  unsigned short* wqb = (unsigned short*)(ws + 37748736);   //  8,388,608
  unsigned short* wkb = (unsigned short*)(ws + 46137344);   //  2,097,152 \ adjacent =
  unsigned short* wvb = (unsigned short*)(ws + 48234496);   //  2,097,152 / wkvb[1024,2048]
  unsigned short* wob = (unsigned short*)(ws + 50331648);   //  8,388,608
  float* qraw = (float*)(ws + 58720256);                    //  8,388,608
  float* kvraw = (float*)(ws + 67108864);                   // 37,748,736 (dead after post)
  float* pO = (float*)(ws + 67108864);                      // 33,554,432 (aliases kvraw)
  float* pML = (float*)(ws + 100663296);                    //     524,288
  unsigned short* qatt = (unsigned short*)(ws + 104857600); //  4,194,304
  unsigned short* katt = (unsigned short*)(ws + 109051904); //  9,437,184
  unsigned short* vtb = (unsigned short*)(ws + 118489088);  //  9,437,184
  unsigned short* attb = (unsigned short*)(ws + 127926272); //  4,194,304
  // total 132,120,576 B

  // 1. convert inputs/weights to bf16 (kv = context||draft per batch)
  conv_kernel<<<dim3(14336), 256, 0, stream>>>(ctx, draft, Wq, Wk, Wv, Wo, kvb, wqb,
                                               wkb, wvb, wob);
  // 2. fused Q/K/V projections (Q: 128 blocks, KV: 576 blocks)
  qkv_kernel<<<dim3(704), 256, 0, stream>>>(kvb, wqb, wkb, qraw, kvraw);
  // 3. RMSNorm+RoPE for Q,K; transpose V
  post_kernel<<<dim3(15616), 256, 0, stream>>>(qraw, kvraw, qw, kw, cpos, dpos, qatt,
                                               katt, vtb);
  // 4. attention, split-K over keys (4 splits)
  attn_kernel<<<dim3(8, 16, 2 * NSPLIT), 256, 0, stream>>>(qatt, katt, vtb, pO, pML);
  // 5. combine partials
  acomb_kernel<<<dim3(8192), 256, 0, stream>>>(pO, pML, attb);
  // 6. out = attn @ Wo^T (split-K x2 + add)
  ogemm_kernel<<<dim3(16, 16, 2), 256, 0, stream>>>(attb, wob, oP);
  addo_kernel<<<dim3(2048), 256, 0, stream>>>(oP, (float*)d_out);
}